// Round 1
// baseline (643.075 us; speedup 1.0000x reference)
//
#include <hip/hip_runtime.h>

#define BB 8
#define NN 2048
#define LL 1280
#define HH 160
#define BN (BB*NN)          // 16384
#define NO (2*HH + LL)      // 1600
#define SHIFT 40.0f

typedef __attribute__((ext_vector_type(8))) short short8;
typedef __attribute__((ext_vector_type(4))) float floatx4;

__device__ __forceinline__ unsigned short f2bf(float f) {
    unsigned int u = __builtin_bit_cast(unsigned int, f);
    u = (u + 0x7FFFu + ((u >> 16) & 1u)) >> 16;
    return (unsigned short)u;
}
__device__ __forceinline__ float bf2f(unsigned short h) {
    unsigned int u = ((unsigned int)h) << 16;
    return __builtin_bit_cast(float, u);
}
__device__ __forceinline__ void split2(float f, unsigned short& hi, unsigned short& lo) {
    hi = f2bf(f);
    lo = f2bf(f - bf2f(hi));
}

// ---------------- cast weights ----------------
__global__ __launch_bounds__(256) void cast_w(
    const float* __restrict__ Wq, const float* __restrict__ Wk, const float* __restrict__ Wv,
    unsigned short* __restrict__ wqk_h, unsigned short* __restrict__ wqk_l,
    unsigned short* __restrict__ wv)
{
    int o = blockIdx.x;   // 0..1599
    if (o < 2*HH) {
        const float* src = (o < HH) ? (Wq + (size_t)o * LL) : (Wk + (size_t)(o - HH) * LL);
        unsigned short* dh = wqk_h + (size_t)o * LL;
        unsigned short* dl = wqk_l + (size_t)o * LL;
        for (int c = threadIdx.x; c < LL; c += 256) {
            unsigned short h, l;
            split2(src[c], h, l);
            dh[c] = h; dl[c] = l;
        }
    } else {
        const float* src = Wv + (size_t)(o - 2*HH) * LL;
        unsigned short* dst = wv + (size_t)(o - 2*HH) * LL;
        for (int c = threadIdx.x * 4; c < LL; c += 256 * 4) {
            float4 f = *(const float4*)(src + c);
            ushort4 u;
            u.x = f2bf(f.x); u.y = f2bf(f.y); u.z = f2bf(f.z); u.w = f2bf(f.w);
            *(ushort4*)(dst + c) = u;
        }
    }
}

// ---------------- Kernel 1a: q,k projection, bf16x2 (3-product MFMA) ----------------
__global__ __launch_bounds__(256, 2) void proj_qk(
    const float* __restrict__ x,
    const unsigned short* __restrict__ wh, const unsigned short* __restrict__ wl,
    const float* __restrict__ bq, const float* __restrict__ bk,
    unsigned short* __restrict__ qh, unsigned short* __restrict__ ql,
    unsigned short* __restrict__ kh, unsigned short* __restrict__ kl)
{
    __shared__ __align__(16) unsigned short Ah[128 * 40];
    __shared__ __align__(16) unsigned short Al[128 * 40];
    __shared__ __align__(16) unsigned short Bh[64 * 40];
    __shared__ __align__(16) unsigned short Bl[64 * 40];

    const int o0 = blockIdx.x * 64;
    const int m0 = blockIdx.y * 128;
    const int tid = threadIdx.x;
    const int wave = tid >> 6, lane = tid & 63;
    const int l15 = lane & 15, l4 = lane >> 4;

    floatx4 acc[2][4] = {};

    const int sr = tid >> 2;          // 0..63
    const int sc = (tid & 3) * 8;     // 0/8/16/24

    for (int k0 = 0; k0 < LL; k0 += 32) {
        __syncthreads();
        #pragma unroll
        for (int h = 0; h < 2; h++) {
            int r = sr + h * 64;
            const float* xp = x + (size_t)(m0 + r) * LL + k0 + sc;
            float4 f0 = *(const float4*)xp;
            float4 f1 = *(const float4*)(xp + 4);
            float fv[8] = {f0.x, f0.y, f0.z, f0.w, f1.x, f1.y, f1.z, f1.w};
            short8 h8, l8;
            #pragma unroll
            for (int i = 0; i < 8; i++) {
                unsigned short hh, lll;
                split2(fv[i], hh, lll);
                h8[i] = (short)hh; l8[i] = (short)lll;
            }
            *(short8*)&Ah[r * 40 + sc] = h8;
            *(short8*)&Al[r * 40 + sc] = l8;
        }
        *(short8*)&Bh[sr * 40 + sc] = *(const short8*)&wh[(size_t)(o0 + sr) * LL + k0 + sc];
        *(short8*)&Bl[sr * 40 + sc] = *(const short8*)&wl[(size_t)(o0 + sr) * LL + k0 + sc];
        __syncthreads();

        short8 ah0 = *(const short8*)&Ah[(wave * 32 + l15) * 40 + l4 * 8];
        short8 ah1 = *(const short8*)&Ah[(wave * 32 + 16 + l15) * 40 + l4 * 8];
        short8 al0 = *(const short8*)&Al[(wave * 32 + l15) * 40 + l4 * 8];
        short8 al1 = *(const short8*)&Al[(wave * 32 + 16 + l15) * 40 + l4 * 8];
        #pragma unroll
        for (int ct = 0; ct < 4; ct++) {
            short8 bh8 = *(const short8*)&Bh[(ct * 16 + l15) * 40 + l4 * 8];
            short8 bl8 = *(const short8*)&Bl[(ct * 16 + l15) * 40 + l4 * 8];
            acc[0][ct] = __builtin_amdgcn_mfma_f32_16x16x32_bf16(ah0, bh8, acc[0][ct], 0, 0, 0);
            acc[0][ct] = __builtin_amdgcn_mfma_f32_16x16x32_bf16(al0, bh8, acc[0][ct], 0, 0, 0);
            acc[0][ct] = __builtin_amdgcn_mfma_f32_16x16x32_bf16(ah0, bl8, acc[0][ct], 0, 0, 0);
            acc[1][ct] = __builtin_amdgcn_mfma_f32_16x16x32_bf16(ah1, bh8, acc[1][ct], 0, 0, 0);
            acc[1][ct] = __builtin_amdgcn_mfma_f32_16x16x32_bf16(al1, bh8, acc[1][ct], 0, 0, 0);
            acc[1][ct] = __builtin_amdgcn_mfma_f32_16x16x32_bf16(ah1, bl8, acc[1][ct], 0, 0, 0);
        }
    }

    #pragma unroll
    for (int rt = 0; rt < 2; rt++)
        #pragma unroll
        for (int ct = 0; ct < 4; ct++)
            #pragma unroll
            for (int r = 0; r < 4; r++) {
                int m = m0 + wave * 32 + rt * 16 + l4 * 4 + r;
                int o = o0 + ct * 16 + l15;
                float val = acc[rt][ct][r] + ((o < HH) ? bq[o] : bk[o - HH]);
                unsigned short vh, vl;
                split2(val, vh, vl);
                if (o < HH) {
                    qh[(size_t)m * HH + o] = vh;
                    ql[(size_t)m * HH + o] = vl;
                } else {
                    kh[(size_t)m * HH + (o - HH)] = vh;
                    kl[(size_t)m * HH + (o - HH)] = vl;
                }
            }
}

// ---------------- Kernel 1b: v projection, bf16 MFMA, transposed output ----------------
__global__ __launch_bounds__(256, 2) void proj_v(
    const float* __restrict__ x, const unsigned short* __restrict__ wv,
    const float* __restrict__ bv, unsigned short* __restrict__ vt)
{
    __shared__ __align__(16) unsigned char smem[128 * 136 * 2];
    unsigned short* As = (unsigned short*)smem;      // [128][40]
    unsigned short* Bs = As + 128 * 40;              // [128][40]

    const int o0 = blockIdx.x * 128;
    const int m0 = blockIdx.y * 128;
    const int tid = threadIdx.x;
    const int wave = tid >> 6, lane = tid & 63;
    const int l15 = lane & 15, l4 = lane >> 4;

    floatx4 acc[2][8] = {};

    const int sr = tid >> 2;
    const int sc = (tid & 3) * 8;

    for (int k0 = 0; k0 < LL; k0 += 32) {
        __syncthreads();
        #pragma unroll
        for (int h = 0; h < 2; h++) {
            int r = sr + h * 64;
            const float* xp = x + (size_t)(m0 + r) * LL + k0 + sc;
            float4 f0 = *(const float4*)xp;
            float4 f1 = *(const float4*)(xp + 4);
            short8 h8;
            h8[0]=(short)f2bf(f0.x); h8[1]=(short)f2bf(f0.y); h8[2]=(short)f2bf(f0.z); h8[3]=(short)f2bf(f0.w);
            h8[4]=(short)f2bf(f1.x); h8[5]=(short)f2bf(f1.y); h8[6]=(short)f2bf(f1.z); h8[7]=(short)f2bf(f1.w);
            *(short8*)&As[r * 40 + sc] = h8;
            *(short8*)&Bs[r * 40 + sc] =
                *(const short8*)&wv[(size_t)(o0 + r) * LL + k0 + sc];
        }
        __syncthreads();
        short8 af0 = *(const short8*)&As[(wave * 32 + l15) * 40 + l4 * 8];
        short8 af1 = *(const short8*)&As[(wave * 32 + 16 + l15) * 40 + l4 * 8];
        #pragma unroll
        for (int ct = 0; ct < 8; ct++) {
            short8 bf = *(const short8*)&Bs[(ct * 16 + l15) * 40 + l4 * 8];
            acc[0][ct] = __builtin_amdgcn_mfma_f32_16x16x32_bf16(af0, bf, acc[0][ct], 0, 0, 0);
            acc[1][ct] = __builtin_amdgcn_mfma_f32_16x16x32_bf16(af1, bf, acc[1][ct], 0, 0, 0);
        }
    }

    __syncthreads();
    unsigned short* trs = (unsigned short*)smem;     // [128 col][136] transpose buf

    #pragma unroll
    for (int rt = 0; rt < 2; rt++)
        #pragma unroll
        for (int ct = 0; ct < 8; ct++)
            #pragma unroll
            for (int r = 0; r < 4; r++) {
                int ml = wave * 32 + rt * 16 + l4 * 4 + r;
                int cl = ct * 16 + l15;
                trs[cl * 136 + ml] = f2bf(acc[rt][ct][r] + bv[o0 + cl]);
            }
    __syncthreads();
    {
        int bidx = m0 >> 11;
        int n0 = m0 & 2047;
        int cl = tid >> 1;
        int f = o0 + cl;
        unsigned short* dst = vt + ((size_t)bidx * LL + f) * NN + n0 + (tid & 1) * 64;
        const unsigned short* srcr = trs + cl * 136 + (tid & 1) * 64;
        #pragma unroll
        for (int i = 0; i < 8; i++)
            *(short8*)(dst + i * 8) = *(const short8*)(srcr + i * 8);
    }
}

// ---------------- Kernel 2a: S = exp(QK^T - SHIFT), row sums ----------------
__global__ __launch_bounds__(256, 2) void s_exp(
    const unsigned short* __restrict__ qhp, const unsigned short* __restrict__ qlp,
    const unsigned short* __restrict__ khp, const unsigned short* __restrict__ klp,
    unsigned short* __restrict__ P, float* __restrict__ Lsum)
{
    __shared__ float sums[4][32];
    const int b  = blockIdx.y;
    const int i0 = blockIdx.x * 32;
    const int tid = threadIdx.x;
    const int wave = tid >> 6, lane = tid & 63;
    const int l15 = lane & 15, l4 = lane >> 4;

    short8 aqh[2][5], aql[2][5];
    #pragma unroll
    for (int rt = 0; rt < 2; rt++) {
        const size_t rowb = ((size_t)b * NN + i0 + rt * 16 + l15) * HH + l4 * 8;
        #pragma unroll
        for (int ks = 0; ks < 5; ks++) {
            aqh[rt][ks] = *(const short8*)&qhp[rowb + ks * 32];
            aql[rt][ks] = *(const short8*)&qlp[rowb + ks * 32];
        }
    }

    float sr[2][4] = {};
    const unsigned short* khB = khp + (size_t)b * NN * HH;
    const unsigned short* klB = klp + (size_t)b * NN * HH;
    unsigned short* Pb = P + (size_t)b * NN * NN;

    for (int c0 = 0; c0 < NN; c0 += 256) {
        const int jb = c0 + wave * 64;      // wave's 64-col stripe
        #pragma unroll
        for (int ct = 0; ct < 4; ct++) {
            const int tok = jb + ct * 16 + l15;
            const size_t kbase = (size_t)tok * HH + l4 * 8;
            floatx4 a0[3] = {{0,0,0,0},{0,0,0,0},{0,0,0,0}};
            floatx4 a1[3] = {{0,0,0,0},{0,0,0,0},{0,0,0,0}};
            #pragma unroll
            for (int ks = 0; ks < 5; ks++) {
                short8 bh = *(const short8*)&khB[kbase + ks * 32];
                short8 bl = *(const short8*)&klB[kbase + ks * 32];
                a0[0] = __builtin_amdgcn_mfma_f32_16x16x32_bf16(aqh[0][ks], bh, a0[0], 0, 0, 0);
                a0[1] = __builtin_amdgcn_mfma_f32_16x16x32_bf16(aql[0][ks], bh, a0[1], 0, 0, 0);
                a0[2] = __builtin_amdgcn_mfma_f32_16x16x32_bf16(aqh[0][ks], bl, a0[2], 0, 0, 0);
                a1[0] = __builtin_amdgcn_mfma_f32_16x16x32_bf16(aqh[1][ks], bh, a1[0], 0, 0, 0);
                a1[1] = __builtin_amdgcn_mfma_f32_16x16x32_bf16(aql[1][ks], bh, a1[1], 0, 0, 0);
                a1[2] = __builtin_amdgcn_mfma_f32_16x16x32_bf16(aqh[1][ks], bl, a1[2], 0, 0, 0);
            }
            #pragma unroll
            for (int r = 0; r < 4; r++) {
                float e0 = a0[0][r] + a0[1][r] + a0[2][r];
                float e1 = a1[0][r] + a1[1][r] + a1[2][r];
                unsigned short pb0 = f2bf(__expf(e0 - SHIFT));
                unsigned short pb1 = f2bf(__expf(e1 - SHIFT));
                Pb[(size_t)(i0 + l4 * 4 + r) * NN + tok] = pb0;
                Pb[(size_t)(i0 + 16 + l4 * 4 + r) * NN + tok] = pb1;
                sr[0][r] += bf2f(pb0);
                sr[1][r] += bf2f(pb1);
            }
        }
    }

    #pragma unroll
    for (int rt = 0; rt < 2; rt++)
        #pragma unroll
        for (int r = 0; r < 4; r++) {
            float v = sr[rt][r];
            v += __shfl_xor(v, 1);
            v += __shfl_xor(v, 2);
            v += __shfl_xor(v, 4);
            v += __shfl_xor(v, 8);
            if (l15 == 0) sums[wave][rt * 16 + l4 * 4 + r] = v;
        }
    __syncthreads();
    if (tid < 32)
        Lsum[(size_t)b * NN + i0 + tid] =
            sums[0][tid] + sums[1][tid] + sums[2][tid] + sums[3][tid];
}

// ---------------- Kernel 2b v2: out = (P x V)/L + x ----------------
// 256x160 tile, BK=32, 512 threads (8 waves, 4Mx2N; wave tile 64x80 = 4x5
// frags). Double-buffered 52 KB LDS staged via global_load_lds dwordx4;
// 2-phase pipeline (issue next-tile staging, compute current, ONE
// drain-barrier per K-step -> load latency hidden under MFMA+ds_read).
// LDS uses a block-transposed granule layout so the linear gload_lds dest
// still yields conflict-floor ds_read_b128 frags:
//   physical granule p(row,c) = (row>>3)*GPR*8... = (row>>3)*32 + c*8 + (row&7)
// (c = 16B granule within the 64B row). Global SOURCE carries the
// permutation (per-lane addresses are free); LDS dest stays linear.
// Grid: 512 blocks = 8 batches x 8 Mtiles x 8 Ntiles = exactly 2 balanced
// rounds on 256 CUs. batch = blockIdx.x&7 -> one batch per XCD (L2 locality),
// n-fastest within XCD for A-panel reuse.
#define PV_BM 256
#define PV_BN 160
#define PV_GRA 1024                 // A granules/buffer: 256 rows * 4
#define PV_GRB 640                  // B granules/buffer: 160 rows * 4
#define PV_GR  (PV_GRA + PV_GRB)    // 1664 granules = 26 KiB

__device__ __forceinline__ void gl16(const unsigned short* g, unsigned short* l) {
    __builtin_amdgcn_global_load_lds(
        (const __attribute__((address_space(1))) unsigned int*)g,
        (__attribute__((address_space(3))) unsigned int*)l, 16, 0, 0);
}

__global__ __launch_bounds__(512, 2) void pv_gemm(
    const unsigned short* __restrict__ P, const unsigned short* __restrict__ vt,
    const float* __restrict__ Lsum,
    const float* __restrict__ x, float* __restrict__ out)
{
    __shared__ __align__(16) unsigned short Sm[2 * PV_GR * 8];   // 52 KiB

    const int flat = blockIdx.x;        // 0..511
    const int b  = flat & 7;            // one batch per XCD
    const int tt = flat >> 3;           // 0..63
    const int m0 = (tt >> 3) * PV_BM;
    const int n0 = (tt & 7) * PV_BN;

    const int tid = threadIdx.x;
    const int wave = tid >> 6, lane = tid & 63;
    const int wm = wave >> 1, wn = wave & 1;
    const int l15 = lane & 15, l4 = lane >> 4;
    const int qa = l15 >> 3, rl = l15 & 7;

    const unsigned short* Pb  = P  + (size_t)b * NN * NN;
    const unsigned short* vtb = vt + (size_t)b * LL * NN;

    floatx4 acc[4][5] = {};

    // ---- staging: 2 A-rounds (1024 granules), 1.25 B-rounds (640) ----
    auto STAGE = [&](int buf, int k0) {
        unsigned short* S = Sm + buf * (PV_GR * 8);
        #pragma unroll
        for (int i = 0; i < 2; i++) {
            int p = i * 512 + tid;                      // physical granule
            int row = (p >> 5) * 8 + (p & 7);
            int c8  = ((p >> 3) & 3) * 8;               // short offset in row
            gl16(Pb + (size_t)(m0 + row) * NN + k0 + c8, S + (size_t)p * 8);
        }
        {
            int p = tid;
            int row = (p >> 5) * 8 + (p & 7);
            int c8  = ((p >> 3) & 3) * 8;
            gl16(vtb + (size_t)(n0 + row) * NN + k0 + c8, S + (size_t)(PV_GRA + p) * 8);
        }
        if (tid < 128) {                                // waves 0-1: uniform
            int p = 512 + tid;
            int row = (p >> 5) * 8 + (p & 7);
            int c8  = ((p >> 3) & 3) * 8;
            gl16(vtb + (size_t)(n0 + row) * NN + k0 + c8, S + (size_t)(PV_GRA + p) * 8);
        }
    };

    // ---- compute one BK=32 step from buffer `buf` ----
    auto COMPUTE = [&](int buf) {
        const unsigned short* S  = Sm + buf * (PV_GR * 8);
        const unsigned short* SB = S + PV_GRA * 8;
        short8 a[4];
        #pragma unroll
        for (int mf = 0; mf < 4; mf++) {
            int p = (wm * 8 + mf * 2 + qa) * 32 + l4 * 8 + rl;
            a[mf] = *(const short8*)(S + p * 8);
        }
        short8 bb[5];
        #pragma unroll
        for (int nf = 0; nf < 5; nf++) {
            int p = (wn * 10 + nf * 2 + qa) * 32 + l4 * 8 + rl;
            bb[nf] = *(const short8*)(SB + p * 8);
        }
        #pragma unroll
        for (int mf = 0; mf < 4; mf++)
            #pragma unroll
            for (int nf = 0; nf < 5; nf++)
                acc[mf][nf] = __builtin_amdgcn_mfma_f32_16x16x32_bf16(a[mf], bb[nf], acc[mf][nf], 0, 0, 0);
    };

    STAGE(0, 0);
    __syncthreads();                    // drains vmcnt: buf0 ready
    int cur = 0;
    for (int t = 0; t < (NN / 32) - 1; t++) {
        STAGE(cur ^ 1, (t + 1) * 32);   // prefetch next K-step
        COMPUTE(cur);                   // hides staging latency
        __syncthreads();                // one drain/barrier per K-step
        cur ^= 1;
    }
    COMPUTE(cur);                       // epilogue step, no prefetch

    float linv[4][4];
    #pragma unroll
    for (int mf = 0; mf < 4; mf++)
        #pragma unroll
        for (int r = 0; r < 4; r++)
            linv[mf][r] = 1.0f / Lsum[(size_t)b * NN + m0 + wm * 64 + mf * 16 + l4 * 4 + r];

    #pragma unroll
    for (int mf = 0; mf < 4; mf++)
        #pragma unroll
        for (int nf = 0; nf < 5; nf++)
            #pragma unroll
            for (int r = 0; r < 4; r++) {
                int row = m0 + wm * 64 + mf * 16 + l4 * 4 + r;
                int col = n0 + wn * 80 + nf * 16 + l15;
                size_t idx = ((size_t)b * NN + row) * LL + col;
                out[idx] = acc[mf][nf][r] * linv[mf][r] + x[idx];
            }
}

extern "C" void kernel_launch(void* const* d_in, const int* in_sizes, int n_in,
                              void* d_out, int out_size, void* d_ws, size_t ws_size,
                              hipStream_t stream) {
    const float* x  = (const float*)d_in[0];
    const float* Wq = (const float*)d_in[1];
    const float* bq = (const float*)d_in[2];
    const float* Wk = (const float*)d_in[3];
    const float* bk = (const float*)d_in[4];
    const float* Wv = (const float*)d_in[5];
    const float* bv = (const float*)d_in[6];
    float* out = (float*)d_out;

    // ws layout (~135 MB)
    unsigned short* wqk_h = (unsigned short*)d_ws;            // [320][LL]
    unsigned short* wqk_l = wqk_h + (size_t)2*HH * LL;        // [320][LL]
    unsigned short* wv    = wqk_l + (size_t)2*HH * LL;        // [LL][LL]
    unsigned short* qh    = wv    + (size_t)LL * LL;          // [BN][HH]
    unsigned short* ql    = qh    + (size_t)BN * HH;
    unsigned short* kh    = ql    + (size_t)BN * HH;
    unsigned short* kl    = kh    + (size_t)BN * HH;
    unsigned short* vt    = kl    + (size_t)BN * HH;          // [BB][LL][NN]
    unsigned short* P     = vt    + (size_t)BB * LL * NN;     // [BB][NN][NN]
    float*          Lsum  = (float*)(P + (size_t)BB * NN * NN); // [BN]

    cast_w<<<dim3(NO), dim3(256), 0, stream>>>(Wq, Wk, Wv, wqk_h, wqk_l, wv);

    dim3 gqk(2*HH / 64, BN / 128);         // (5, 128)
    proj_qk<<<gqk, dim3(256), 0, stream>>>(x, wqk_h, wqk_l, bq, bk, qh, ql, kh, kl);

    dim3 gv(LL / 128, BN / 128);           // (10, 128)
    proj_v<<<gv, dim3(256), 0, stream>>>(x, wv, bv, vt);

    dim3 gs(NN / 32, BB);                  // (64, 8)
    s_exp<<<gs, dim3(256), 0, stream>>>(qh, ql, kh, kl, P, Lsum);

    // 512 blocks: 8 batches x 8 Mtiles x 8 Ntiles, 512 threads each
    pv_gemm<<<dim3(512), dim3(512), 0, stream>>>(P, vt, Lsum, x, out);
}

// Round 2
// 622.944 us; speedup vs baseline: 1.0323x; 1.0323x over previous
//
#include <hip/hip_runtime.h>

#define BB 8
#define NN 2048
#define LL 1280
#define HH 160
#define BN (BB*NN)          // 16384
#define NO (2*HH + LL)      // 1600
#define SHIFT 40.0f

typedef __attribute__((ext_vector_type(8))) short short8;
typedef __attribute__((ext_vector_type(4))) float floatx4;

__device__ __forceinline__ unsigned short f2bf(float f) {
    unsigned int u = __builtin_bit_cast(unsigned int, f);
    u = (u + 0x7FFFu + ((u >> 16) & 1u)) >> 16;
    return (unsigned short)u;
}
__device__ __forceinline__ float bf2f(unsigned short h) {
    unsigned int u = ((unsigned int)h) << 16;
    return __builtin_bit_cast(float, u);
}
__device__ __forceinline__ void split2(float f, unsigned short& hi, unsigned short& lo) {
    hi = f2bf(f);
    lo = f2bf(f - bf2f(hi));
}

// ---------------- cast weights ----------------
__global__ __launch_bounds__(256) void cast_w(
    const float* __restrict__ Wq, const float* __restrict__ Wk, const float* __restrict__ Wv,
    unsigned short* __restrict__ wqk_h, unsigned short* __restrict__ wqk_l,
    unsigned short* __restrict__ wv)
{
    int o = blockIdx.x;   // 0..1599
    if (o < 2*HH) {
        const float* src = (o < HH) ? (Wq + (size_t)o * LL) : (Wk + (size_t)(o - HH) * LL);
        unsigned short* dh = wqk_h + (size_t)o * LL;
        unsigned short* dl = wqk_l + (size_t)o * LL;
        for (int c = threadIdx.x; c < LL; c += 256) {
            unsigned short h, l;
            split2(src[c], h, l);
            dh[c] = h; dl[c] = l;
        }
    } else {
        const float* src = Wv + (size_t)(o - 2*HH) * LL;
        unsigned short* dst = wv + (size_t)(o - 2*HH) * LL;
        for (int c = threadIdx.x * 4; c < LL; c += 256 * 4) {
            float4 f = *(const float4*)(src + c);
            ushort4 u;
            u.x = f2bf(f.x); u.y = f2bf(f.y); u.z = f2bf(f.z); u.w = f2bf(f.w);
            *(ushort4*)(dst + c) = u;
        }
    }
}

// ---------------- Kernel 1a: q,k projection, bf16x2 (3-product MFMA) ----------------
__global__ __launch_bounds__(256, 2) void proj_qk(
    const float* __restrict__ x,
    const unsigned short* __restrict__ wh, const unsigned short* __restrict__ wl,
    const float* __restrict__ bq, const float* __restrict__ bk,
    unsigned short* __restrict__ qh, unsigned short* __restrict__ ql,
    unsigned short* __restrict__ kh, unsigned short* __restrict__ kl)
{
    __shared__ __align__(16) unsigned short Ah[128 * 40];
    __shared__ __align__(16) unsigned short Al[128 * 40];
    __shared__ __align__(16) unsigned short Bh[64 * 40];
    __shared__ __align__(16) unsigned short Bl[64 * 40];

    const int o0 = blockIdx.x * 64;
    const int m0 = blockIdx.y * 128;
    const int tid = threadIdx.x;
    const int wave = tid >> 6, lane = tid & 63;
    const int l15 = lane & 15, l4 = lane >> 4;

    floatx4 acc[2][4] = {};

    const int sr = tid >> 2;          // 0..63
    const int sc = (tid & 3) * 8;     // 0/8/16/24

    for (int k0 = 0; k0 < LL; k0 += 32) {
        __syncthreads();
        #pragma unroll
        for (int h = 0; h < 2; h++) {
            int r = sr + h * 64;
            const float* xp = x + (size_t)(m0 + r) * LL + k0 + sc;
            float4 f0 = *(const float4*)xp;
            float4 f1 = *(const float4*)(xp + 4);
            float fv[8] = {f0.x, f0.y, f0.z, f0.w, f1.x, f1.y, f1.z, f1.w};
            short8 h8, l8;
            #pragma unroll
            for (int i = 0; i < 8; i++) {
                unsigned short hh, lll;
                split2(fv[i], hh, lll);
                h8[i] = (short)hh; l8[i] = (short)lll;
            }
            *(short8*)&Ah[r * 40 + sc] = h8;
            *(short8*)&Al[r * 40 + sc] = l8;
        }
        *(short8*)&Bh[sr * 40 + sc] = *(const short8*)&wh[(size_t)(o0 + sr) * LL + k0 + sc];
        *(short8*)&Bl[sr * 40 + sc] = *(const short8*)&wl[(size_t)(o0 + sr) * LL + k0 + sc];
        __syncthreads();

        short8 ah0 = *(const short8*)&Ah[(wave * 32 + l15) * 40 + l4 * 8];
        short8 ah1 = *(const short8*)&Ah[(wave * 32 + 16 + l15) * 40 + l4 * 8];
        short8 al0 = *(const short8*)&Al[(wave * 32 + l15) * 40 + l4 * 8];
        short8 al1 = *(const short8*)&Al[(wave * 32 + 16 + l15) * 40 + l4 * 8];
        #pragma unroll
        for (int ct = 0; ct < 4; ct++) {
            short8 bh8 = *(const short8*)&Bh[(ct * 16 + l15) * 40 + l4 * 8];
            short8 bl8 = *(const short8*)&Bl[(ct * 16 + l15) * 40 + l4 * 8];
            acc[0][ct] = __builtin_amdgcn_mfma_f32_16x16x32_bf16(ah0, bh8, acc[0][ct], 0, 0, 0);
            acc[0][ct] = __builtin_amdgcn_mfma_f32_16x16x32_bf16(al0, bh8, acc[0][ct], 0, 0, 0);
            acc[0][ct] = __builtin_amdgcn_mfma_f32_16x16x32_bf16(ah0, bl8, acc[0][ct], 0, 0, 0);
            acc[1][ct] = __builtin_amdgcn_mfma_f32_16x16x32_bf16(ah1, bh8, acc[1][ct], 0, 0, 0);
            acc[1][ct] = __builtin_amdgcn_mfma_f32_16x16x32_bf16(al1, bh8, acc[1][ct], 0, 0, 0);
            acc[1][ct] = __builtin_amdgcn_mfma_f32_16x16x32_bf16(ah1, bl8, acc[1][ct], 0, 0, 0);
        }
    }

    #pragma unroll
    for (int rt = 0; rt < 2; rt++)
        #pragma unroll
        for (int ct = 0; ct < 4; ct++)
            #pragma unroll
            for (int r = 0; r < 4; r++) {
                int m = m0 + wave * 32 + rt * 16 + l4 * 4 + r;
                int o = o0 + ct * 16 + l15;
                float val = acc[rt][ct][r] + ((o < HH) ? bq[o] : bk[o - HH]);
                unsigned short vh, vl;
                split2(val, vh, vl);
                if (o < HH) {
                    qh[(size_t)m * HH + o] = vh;
                    ql[(size_t)m * HH + o] = vl;
                } else {
                    kh[(size_t)m * HH + (o - HH)] = vh;
                    kl[(size_t)m * HH + (o - HH)] = vl;
                }
            }
}

// ---------------- Kernel 1b: v projection, bf16 MFMA, transposed output ----------------
__global__ __launch_bounds__(256, 2) void proj_v(
    const float* __restrict__ x, const unsigned short* __restrict__ wv,
    const float* __restrict__ bv, unsigned short* __restrict__ vt)
{
    __shared__ __align__(16) unsigned char smem[128 * 136 * 2];
    unsigned short* As = (unsigned short*)smem;      // [128][40]
    unsigned short* Bs = As + 128 * 40;              // [128][40]

    const int o0 = blockIdx.x * 128;
    const int m0 = blockIdx.y * 128;
    const int tid = threadIdx.x;
    const int wave = tid >> 6, lane = tid & 63;
    const int l15 = lane & 15, l4 = lane >> 4;

    floatx4 acc[2][8] = {};

    const int sr = tid >> 2;
    const int sc = (tid & 3) * 8;

    for (int k0 = 0; k0 < LL; k0 += 32) {
        __syncthreads();
        #pragma unroll
        for (int h = 0; h < 2; h++) {
            int r = sr + h * 64;
            const float* xp = x + (size_t)(m0 + r) * LL + k0 + sc;
            float4 f0 = *(const float4*)xp;
            float4 f1 = *(const float4*)(xp + 4);
            short8 h8;
            h8[0]=(short)f2bf(f0.x); h8[1]=(short)f2bf(f0.y); h8[2]=(short)f2bf(f0.z); h8[3]=(short)f2bf(f0.w);
            h8[4]=(short)f2bf(f1.x); h8[5]=(short)f2bf(f1.y); h8[6]=(short)f2bf(f1.z); h8[7]=(short)f2bf(f1.w);
            *(short8*)&As[r * 40 + sc] = h8;
            *(short8*)&Bs[r * 40 + sc] =
                *(const short8*)&wv[(size_t)(o0 + r) * LL + k0 + sc];
        }
        __syncthreads();
        short8 af0 = *(const short8*)&As[(wave * 32 + l15) * 40 + l4 * 8];
        short8 af1 = *(const short8*)&As[(wave * 32 + 16 + l15) * 40 + l4 * 8];
        #pragma unroll
        for (int ct = 0; ct < 8; ct++) {
            short8 bf = *(const short8*)&Bs[(ct * 16 + l15) * 40 + l4 * 8];
            acc[0][ct] = __builtin_amdgcn_mfma_f32_16x16x32_bf16(af0, bf, acc[0][ct], 0, 0, 0);
            acc[1][ct] = __builtin_amdgcn_mfma_f32_16x16x32_bf16(af1, bf, acc[1][ct], 0, 0, 0);
        }
    }

    __syncthreads();
    unsigned short* trs = (unsigned short*)smem;     // [128 col][136] transpose buf

    #pragma unroll
    for (int rt = 0; rt < 2; rt++)
        #pragma unroll
        for (int ct = 0; ct < 8; ct++)
            #pragma unroll
            for (int r = 0; r < 4; r++) {
                int ml = wave * 32 + rt * 16 + l4 * 4 + r;
                int cl = ct * 16 + l15;
                trs[cl * 136 + ml] = f2bf(acc[rt][ct][r] + bv[o0 + cl]);
            }
    __syncthreads();
    {
        int bidx = m0 >> 11;
        int n0 = m0 & 2047;
        int cl = tid >> 1;
        int f = o0 + cl;
        unsigned short* dst = vt + ((size_t)bidx * LL + f) * NN + n0 + (tid & 1) * 64;
        const unsigned short* srcr = trs + cl * 136 + (tid & 1) * 64;
        #pragma unroll
        for (int i = 0; i < 8; i++)
            *(short8*)(dst + i * 8) = *(const short8*)(srcr + i * 8);
    }
}

// ---------------- Kernel 2a: S = exp(QK^T - SHIFT), row sums ----------------
__global__ __launch_bounds__(256, 2) void s_exp(
    const unsigned short* __restrict__ qhp, const unsigned short* __restrict__ qlp,
    const unsigned short* __restrict__ khp, const unsigned short* __restrict__ klp,
    unsigned short* __restrict__ P, float* __restrict__ Lsum)
{
    __shared__ float sums[4][32];
    const int b  = blockIdx.y;
    const int i0 = blockIdx.x * 32;
    const int tid = threadIdx.x;
    const int wave = tid >> 6, lane = tid & 63;
    const int l15 = lane & 15, l4 = lane >> 4;

    short8 aqh[2][5], aql[2][5];
    #pragma unroll
    for (int rt = 0; rt < 2; rt++) {
        const size_t rowb = ((size_t)b * NN + i0 + rt * 16 + l15) * HH + l4 * 8;
        #pragma unroll
        for (int ks = 0; ks < 5; ks++) {
            aqh[rt][ks] = *(const short8*)&qhp[rowb + ks * 32];
            aql[rt][ks] = *(const short8*)&qlp[rowb + ks * 32];
        }
    }

    float sr[2][4] = {};
    const unsigned short* khB = khp + (size_t)b * NN * HH;
    const unsigned short* klB = klp + (size_t)b * NN * HH;
    unsigned short* Pb = P + (size_t)b * NN * NN;

    for (int c0 = 0; c0 < NN; c0 += 256) {
        const int jb = c0 + wave * 64;      // wave's 64-col stripe
        #pragma unroll
        for (int ct = 0; ct < 4; ct++) {
            const int tok = jb + ct * 16 + l15;
            const size_t kbase = (size_t)tok * HH + l4 * 8;
            floatx4 a0[3] = {{0,0,0,0},{0,0,0,0},{0,0,0,0}};
            floatx4 a1[3] = {{0,0,0,0},{0,0,0,0},{0,0,0,0}};
            #pragma unroll
            for (int ks = 0; ks < 5; ks++) {
                short8 bh = *(const short8*)&khB[kbase + ks * 32];
                short8 bl = *(const short8*)&klB[kbase + ks * 32];
                a0[0] = __builtin_amdgcn_mfma_f32_16x16x32_bf16(aqh[0][ks], bh, a0[0], 0, 0, 0);
                a0[1] = __builtin_amdgcn_mfma_f32_16x16x32_bf16(aql[0][ks], bh, a0[1], 0, 0, 0);
                a0[2] = __builtin_amdgcn_mfma_f32_16x16x32_bf16(aqh[0][ks], bl, a0[2], 0, 0, 0);
                a1[0] = __builtin_amdgcn_mfma_f32_16x16x32_bf16(aqh[1][ks], bh, a1[0], 0, 0, 0);
                a1[1] = __builtin_amdgcn_mfma_f32_16x16x32_bf16(aql[1][ks], bh, a1[1], 0, 0, 0);
                a1[2] = __builtin_amdgcn_mfma_f32_16x16x32_bf16(aqh[1][ks], bl, a1[2], 0, 0, 0);
            }
            #pragma unroll
            for (int r = 0; r < 4; r++) {
                float e0 = a0[0][r] + a0[1][r] + a0[2][r];
                float e1 = a1[0][r] + a1[1][r] + a1[2][r];
                unsigned short pb0 = f2bf(__expf(e0 - SHIFT));
                unsigned short pb1 = f2bf(__expf(e1 - SHIFT));
                Pb[(size_t)(i0 + l4 * 4 + r) * NN + tok] = pb0;
                Pb[(size_t)(i0 + 16 + l4 * 4 + r) * NN + tok] = pb1;
                sr[0][r] += bf2f(pb0);
                sr[1][r] += bf2f(pb1);
            }
        }
    }

    #pragma unroll
    for (int rt = 0; rt < 2; rt++)
        #pragma unroll
        for (int r = 0; r < 4; r++) {
            float v = sr[rt][r];
            v += __shfl_xor(v, 1);
            v += __shfl_xor(v, 2);
            v += __shfl_xor(v, 4);
            v += __shfl_xor(v, 8);
            if (l15 == 0) sums[wave][rt * 16 + l4 * 4 + r] = v;
        }
    __syncthreads();
    if (tid < 32)
        Lsum[(size_t)b * NN + i0 + tid] =
            sums[0][tid] + sums[1][tid] + sums[2][tid] + sums[3][tid];
}

// ---------------- Kernel 2b v3: out = (P x V)/L + x ----------------
// m97 structure: 128x128 tile, BK=32, 256 threads (4 waves, each 32x128),
// SINGLE-buffer LDS, 2 barriers per K-step, 5 blocks/CU (1280 blocks) for
// implicit wave-level overlap. Staging via global_load_lds dwordx4 into a
// granule-transposed linear layout (verified 0 bank conflicts in round 1):
//   physical granule p(row,c) = (row>>3)*32 + c*8 + (row&7), c = 16B granule
// Global SOURCE carries the permutation; LDS dest stays linear (rule #21).
// XCD swizzle: flat 1280 blocks, b = bid&7 -> each XCD owns one batch, its
// P-panels reused across the 10 N-tiles in its own L2.
__device__ __forceinline__ void gl16(const unsigned short* g, unsigned short* l) {
    __builtin_amdgcn_global_load_lds(
        (const __attribute__((address_space(1))) unsigned int*)g,
        (__attribute__((address_space(3))) unsigned int*)l, 16, 0, 0);
}

__global__ __launch_bounds__(256, 2) void pv_gemm(
    const unsigned short* __restrict__ P, const unsigned short* __restrict__ vt,
    const float* __restrict__ Lsum,
    const float* __restrict__ x, float* __restrict__ out)
{
    __shared__ __align__(16) unsigned short As[512 * 8];   // 8 KiB, 512 granules
    __shared__ __align__(16) unsigned short Bs[512 * 8];   // 8 KiB

    const int p0 = blockIdx.x;          // 0..1279
    const int b  = p0 & 7;              // one batch per XCD
    const int t  = p0 >> 3;             // 0..159
    const int n0 = (t % 10) * 128;
    const int m0 = (t / 10) * 128;

    const int tid = threadIdx.x;
    const int wave = tid >> 6, lane = tid & 63;
    const int l15 = lane & 15, l4 = lane >> 4;
    const int qa = l15 >> 3, rl = l15 & 7;

    const unsigned short* Pb  = P  + (size_t)b * NN * NN;
    const unsigned short* vtb = vt + (size_t)b * LL * NN;

    floatx4 acc[2][8] = {};

    for (int k0 = 0; k0 < NN; k0 += 32) {
        __syncthreads();                 // everyone done reading LDS
        #pragma unroll
        for (int i = 0; i < 2; i++) {
            int p = i * 256 + tid;                       // physical granule
            int row = ((p >> 5) << 3) + (p & 7);
            int c8  = ((p >> 3) & 3) * 8;                // short offset in row
            gl16(Pb  + (size_t)(m0 + row) * NN + k0 + c8, As + p * 8);
            gl16(vtb + (size_t)(n0 + row) * NN + k0 + c8, Bs + p * 8);
        }
        __syncthreads();                 // drains vmcnt: tile ready

        short8 af0, af1;
        {
            int pa0 = (wave * 4 + 0 + qa) * 32 + l4 * 8 + rl;   // rows wave*32+l15
            int pa1 = (wave * 4 + 2 + qa) * 32 + l4 * 8 + rl;   // rows wave*32+16+l15
            af0 = *(const short8*)(As + pa0 * 8);
            af1 = *(const short8*)(As + pa1 * 8);
        }
        #pragma unroll
        for (int ct = 0; ct < 8; ct++) {
            int pb = (ct * 2 + qa) * 32 + l4 * 8 + rl;          // rows ct*16+l15
            short8 bf = *(const short8*)(Bs + pb * 8);
            acc[0][ct] = __builtin_amdgcn_mfma_f32_16x16x32_bf16(af0, bf, acc[0][ct], 0, 0, 0);
            acc[1][ct] = __builtin_amdgcn_mfma_f32_16x16x32_bf16(af1, bf, acc[1][ct], 0, 0, 0);
        }
    }

    float linv[2][4];
    #pragma unroll
    for (int rt = 0; rt < 2; rt++)
        #pragma unroll
        for (int r = 0; r < 4; r++)
            linv[rt][r] = 1.0f / Lsum[(size_t)b * NN + m0 + wave * 32 + rt * 16 + l4 * 4 + r];

    #pragma unroll
    for (int rt = 0; rt < 2; rt++)
        #pragma unroll
        for (int ct = 0; ct < 8; ct++)
            #pragma unroll
            for (int r = 0; r < 4; r++) {
                int row = m0 + wave * 32 + rt * 16 + l4 * 4 + r;
                int col = n0 + ct * 16 + l15;
                size_t idx = ((size_t)b * NN + row) * LL + col;
                out[idx] = acc[rt][ct][r] * linv[rt][r] + x[idx];
            }
}

extern "C" void kernel_launch(void* const* d_in, const int* in_sizes, int n_in,
                              void* d_out, int out_size, void* d_ws, size_t ws_size,
                              hipStream_t stream) {
    const float* x  = (const float*)d_in[0];
    const float* Wq = (const float*)d_in[1];
    const float* bq = (const float*)d_in[2];
    const float* Wk = (const float*)d_in[3];
    const float* bk = (const float*)d_in[4];
    const float* Wv = (const float*)d_in[5];
    const float* bv = (const float*)d_in[6];
    float* out = (float*)d_out;

    // ws layout (~135 MB)
    unsigned short* wqk_h = (unsigned short*)d_ws;            // [320][LL]
    unsigned short* wqk_l = wqk_h + (size_t)2*HH * LL;        // [320][LL]
    unsigned short* wv    = wqk_l + (size_t)2*HH * LL;        // [LL][LL]
    unsigned short* qh    = wv    + (size_t)LL * LL;          // [BN][HH]
    unsigned short* ql    = qh    + (size_t)BN * HH;
    unsigned short* kh    = ql    + (size_t)BN * HH;
    unsigned short* kl    = kh    + (size_t)BN * HH;
    unsigned short* vt    = kl    + (size_t)BN * HH;          // [BB][LL][NN]
    unsigned short* P     = vt    + (size_t)BB * LL * NN;     // [BB][NN][NN]
    float*          Lsum  = (float*)(P + (size_t)BB * NN * NN); // [BN]

    cast_w<<<dim3(NO), dim3(256), 0, stream>>>(Wq, Wk, Wv, wqk_h, wqk_l, wv);

    dim3 gqk(2*HH / 64, BN / 128);         // (5, 128)
    proj_qk<<<gqk, dim3(256), 0, stream>>>(x, wqk_h, wqk_l, bq, bk, qh, ql, kh, kl);

    dim3 gv(LL / 128, BN / 128);           // (10, 128)
    proj_v<<<gv, dim3(256), 0, stream>>>(x, wv, bv, vt);

    dim3 gs(NN / 32, BB);                  // (64, 8)
    s_exp<<<gs, dim3(256), 0, stream>>>(qh, ql, kh, kl, P, Lsum);

    // flat 1280 blocks: b = bid&7 (batch per XCD), t = bid>>3 -> (n,m) tile
    pv_gemm<<<dim3(1280), dim3(256), 0, stream>>>(P, vt, Lsum, x, out);
}

// Round 3
// 605.048 us; speedup vs baseline: 1.0628x; 1.0296x over previous
//
#include <hip/hip_runtime.h>

#define BB 8
#define NN 2048
#define LL 1280
#define HH 160
#define BN (BB*NN)          // 16384
#define NO (2*HH + LL)      // 1600
#define SHIFT 40.0f

typedef __attribute__((ext_vector_type(8))) short short8;
typedef __attribute__((ext_vector_type(4))) float floatx4;

__device__ __forceinline__ unsigned short f2bf(float f) {
    unsigned int u = __builtin_bit_cast(unsigned int, f);
    u = (u + 0x7FFFu + ((u >> 16) & 1u)) >> 16;
    return (unsigned short)u;
}
__device__ __forceinline__ float bf2f(unsigned short h) {
    unsigned int u = ((unsigned int)h) << 16;
    return __builtin_bit_cast(float, u);
}
__device__ __forceinline__ void split2(float f, unsigned short& hi, unsigned short& lo) {
    hi = f2bf(f);
    lo = f2bf(f - bf2f(hi));
}

// ---------------- cast weights ----------------
__global__ __launch_bounds__(256) void cast_w(
    const float* __restrict__ Wq, const float* __restrict__ Wk, const float* __restrict__ Wv,
    unsigned short* __restrict__ wqk_h, unsigned short* __restrict__ wqk_l,
    unsigned short* __restrict__ wv)
{
    int o = blockIdx.x;   // 0..1599
    if (o < 2*HH) {
        const float* src = (o < HH) ? (Wq + (size_t)o * LL) : (Wk + (size_t)(o - HH) * LL);
        unsigned short* dh = wqk_h + (size_t)o * LL;
        unsigned short* dl = wqk_l + (size_t)o * LL;
        for (int c = threadIdx.x; c < LL; c += 256) {
            unsigned short h, l;
            split2(src[c], h, l);
            dh[c] = h; dl[c] = l;
        }
    } else {
        const float* src = Wv + (size_t)(o - 2*HH) * LL;
        unsigned short* dst = wv + (size_t)(o - 2*HH) * LL;
        for (int c = threadIdx.x * 4; c < LL; c += 256 * 4) {
            float4 f = *(const float4*)(src + c);
            ushort4 u;
            u.x = f2bf(f.x); u.y = f2bf(f.y); u.z = f2bf(f.z); u.w = f2bf(f.w);
            *(ushort4*)(dst + c) = u;
        }
    }
}

// ---------------- Kernel 1a: q,k projection, bf16x2 (3-product MFMA) ----------------
__global__ __launch_bounds__(256, 2) void proj_qk(
    const float* __restrict__ x,
    const unsigned short* __restrict__ wh, const unsigned short* __restrict__ wl,
    const float* __restrict__ bq, const float* __restrict__ bk,
    unsigned short* __restrict__ qh, unsigned short* __restrict__ ql,
    unsigned short* __restrict__ kh, unsigned short* __restrict__ kl)
{
    __shared__ __align__(16) unsigned short Ah[128 * 40];
    __shared__ __align__(16) unsigned short Al[128 * 40];
    __shared__ __align__(16) unsigned short Bh[64 * 40];
    __shared__ __align__(16) unsigned short Bl[64 * 40];

    const int o0 = blockIdx.x * 64;
    const int m0 = blockIdx.y * 128;
    const int tid = threadIdx.x;
    const int wave = tid >> 6, lane = tid & 63;
    const int l15 = lane & 15, l4 = lane >> 4;

    floatx4 acc[2][4] = {};

    const int sr = tid >> 2;          // 0..63
    const int sc = (tid & 3) * 8;     // 0/8/16/24

    for (int k0 = 0; k0 < LL; k0 += 32) {
        __syncthreads();
        #pragma unroll
        for (int h = 0; h < 2; h++) {
            int r = sr + h * 64;
            const float* xp = x + (size_t)(m0 + r) * LL + k0 + sc;
            float4 f0 = *(const float4*)xp;
            float4 f1 = *(const float4*)(xp + 4);
            float fv[8] = {f0.x, f0.y, f0.z, f0.w, f1.x, f1.y, f1.z, f1.w};
            short8 h8, l8;
            #pragma unroll
            for (int i = 0; i < 8; i++) {
                unsigned short hh, lll;
                split2(fv[i], hh, lll);
                h8[i] = (short)hh; l8[i] = (short)lll;
            }
            *(short8*)&Ah[r * 40 + sc] = h8;
            *(short8*)&Al[r * 40 + sc] = l8;
        }
        *(short8*)&Bh[sr * 40 + sc] = *(const short8*)&wh[(size_t)(o0 + sr) * LL + k0 + sc];
        *(short8*)&Bl[sr * 40 + sc] = *(const short8*)&wl[(size_t)(o0 + sr) * LL + k0 + sc];
        __syncthreads();

        short8 ah0 = *(const short8*)&Ah[(wave * 32 + l15) * 40 + l4 * 8];
        short8 ah1 = *(const short8*)&Ah[(wave * 32 + 16 + l15) * 40 + l4 * 8];
        short8 al0 = *(const short8*)&Al[(wave * 32 + l15) * 40 + l4 * 8];
        short8 al1 = *(const short8*)&Al[(wave * 32 + 16 + l15) * 40 + l4 * 8];
        #pragma unroll
        for (int ct = 0; ct < 4; ct++) {
            short8 bh8 = *(const short8*)&Bh[(ct * 16 + l15) * 40 + l4 * 8];
            short8 bl8 = *(const short8*)&Bl[(ct * 16 + l15) * 40 + l4 * 8];
            acc[0][ct] = __builtin_amdgcn_mfma_f32_16x16x32_bf16(ah0, bh8, acc[0][ct], 0, 0, 0);
            acc[0][ct] = __builtin_amdgcn_mfma_f32_16x16x32_bf16(al0, bh8, acc[0][ct], 0, 0, 0);
            acc[0][ct] = __builtin_amdgcn_mfma_f32_16x16x32_bf16(ah0, bl8, acc[0][ct], 0, 0, 0);
            acc[1][ct] = __builtin_amdgcn_mfma_f32_16x16x32_bf16(ah1, bh8, acc[1][ct], 0, 0, 0);
            acc[1][ct] = __builtin_amdgcn_mfma_f32_16x16x32_bf16(al1, bh8, acc[1][ct], 0, 0, 0);
            acc[1][ct] = __builtin_amdgcn_mfma_f32_16x16x32_bf16(ah1, bl8, acc[1][ct], 0, 0, 0);
        }
    }

    #pragma unroll
    for (int rt = 0; rt < 2; rt++)
        #pragma unroll
        for (int ct = 0; ct < 4; ct++)
            #pragma unroll
            for (int r = 0; r < 4; r++) {
                int m = m0 + wave * 32 + rt * 16 + l4 * 4 + r;
                int o = o0 + ct * 16 + l15;
                float val = acc[rt][ct][r] + ((o < HH) ? bq[o] : bk[o - HH]);
                unsigned short vh, vl;
                split2(val, vh, vl);
                if (o < HH) {
                    qh[(size_t)m * HH + o] = vh;
                    ql[(size_t)m * HH + o] = vl;
                } else {
                    kh[(size_t)m * HH + (o - HH)] = vh;
                    kl[(size_t)m * HH + (o - HH)] = vl;
                }
            }
}

// ---------------- Kernel 1b: v projection, bf16 MFMA, transposed output ----------------
__global__ __launch_bounds__(256, 2) void proj_v(
    const float* __restrict__ x, const unsigned short* __restrict__ wv,
    const float* __restrict__ bv, unsigned short* __restrict__ vt)
{
    __shared__ __align__(16) unsigned char smem[128 * 136 * 2];
    unsigned short* As = (unsigned short*)smem;      // [128][40]
    unsigned short* Bs = As + 128 * 40;              // [128][40]

    const int o0 = blockIdx.x * 128;
    const int m0 = blockIdx.y * 128;
    const int tid = threadIdx.x;
    const int wave = tid >> 6, lane = tid & 63;
    const int l15 = lane & 15, l4 = lane >> 4;

    floatx4 acc[2][8] = {};

    const int sr = tid >> 2;
    const int sc = (tid & 3) * 8;

    for (int k0 = 0; k0 < LL; k0 += 32) {
        __syncthreads();
        #pragma unroll
        for (int h = 0; h < 2; h++) {
            int r = sr + h * 64;
            const float* xp = x + (size_t)(m0 + r) * LL + k0 + sc;
            float4 f0 = *(const float4*)xp;
            float4 f1 = *(const float4*)(xp + 4);
            short8 h8;
            h8[0]=(short)f2bf(f0.x); h8[1]=(short)f2bf(f0.y); h8[2]=(short)f2bf(f0.z); h8[3]=(short)f2bf(f0.w);
            h8[4]=(short)f2bf(f1.x); h8[5]=(short)f2bf(f1.y); h8[6]=(short)f2bf(f1.z); h8[7]=(short)f2bf(f1.w);
            *(short8*)&As[r * 40 + sc] = h8;
            *(short8*)&Bs[r * 40 + sc] =
                *(const short8*)&wv[(size_t)(o0 + r) * LL + k0 + sc];
        }
        __syncthreads();
        short8 af0 = *(const short8*)&As[(wave * 32 + l15) * 40 + l4 * 8];
        short8 af1 = *(const short8*)&As[(wave * 32 + 16 + l15) * 40 + l4 * 8];
        #pragma unroll
        for (int ct = 0; ct < 8; ct++) {
            short8 bf = *(const short8*)&Bs[(ct * 16 + l15) * 40 + l4 * 8];
            acc[0][ct] = __builtin_amdgcn_mfma_f32_16x16x32_bf16(af0, bf, acc[0][ct], 0, 0, 0);
            acc[1][ct] = __builtin_amdgcn_mfma_f32_16x16x32_bf16(af1, bf, acc[1][ct], 0, 0, 0);
        }
    }

    __syncthreads();
    unsigned short* trs = (unsigned short*)smem;     // [128 col][136] transpose buf

    #pragma unroll
    for (int rt = 0; rt < 2; rt++)
        #pragma unroll
        for (int ct = 0; ct < 8; ct++)
            #pragma unroll
            for (int r = 0; r < 4; r++) {
                int ml = wave * 32 + rt * 16 + l4 * 4 + r;
                int cl = ct * 16 + l15;
                trs[cl * 136 + ml] = f2bf(acc[rt][ct][r] + bv[o0 + cl]);
            }
    __syncthreads();
    {
        int bidx = m0 >> 11;
        int n0 = m0 & 2047;
        int cl = tid >> 1;
        int f = o0 + cl;
        unsigned short* dst = vt + ((size_t)bidx * LL + f) * NN + n0 + (tid & 1) * 64;
        const unsigned short* srcr = trs + cl * 136 + (tid & 1) * 64;
        #pragma unroll
        for (int i = 0; i < 8; i++)
            *(short8*)(dst + i * 8) = *(const short8*)(srcr + i * 8);
    }
}

// ---------------- Kernel 2a: S = exp(QK^T - SHIFT), row sums ----------------
__global__ __launch_bounds__(256, 2) void s_exp(
    const unsigned short* __restrict__ qhp, const unsigned short* __restrict__ qlp,
    const unsigned short* __restrict__ khp, const unsigned short* __restrict__ klp,
    unsigned short* __restrict__ P, float* __restrict__ Lsum)
{
    __shared__ float sums[4][32];
    const int b  = blockIdx.y;
    const int i0 = blockIdx.x * 32;
    const int tid = threadIdx.x;
    const int wave = tid >> 6, lane = tid & 63;
    const int l15 = lane & 15, l4 = lane >> 4;

    short8 aqh[2][5], aql[2][5];
    #pragma unroll
    for (int rt = 0; rt < 2; rt++) {
        const size_t rowb = ((size_t)b * NN + i0 + rt * 16 + l15) * HH + l4 * 8;
        #pragma unroll
        for (int ks = 0; ks < 5; ks++) {
            aqh[rt][ks] = *(const short8*)&qhp[rowb + ks * 32];
            aql[rt][ks] = *(const short8*)&qlp[rowb + ks * 32];
        }
    }

    float sr[2][4] = {};
    const unsigned short* khB = khp + (size_t)b * NN * HH;
    const unsigned short* klB = klp + (size_t)b * NN * HH;
    unsigned short* Pb = P + (size_t)b * NN * NN;

    for (int c0 = 0; c0 < NN; c0 += 256) {
        const int jb = c0 + wave * 64;      // wave's 64-col stripe
        #pragma unroll
        for (int ct = 0; ct < 4; ct++) {
            const int tok = jb + ct * 16 + l15;
            const size_t kbase = (size_t)tok * HH + l4 * 8;
            floatx4 a0[3] = {{0,0,0,0},{0,0,0,0},{0,0,0,0}};
            floatx4 a1[3] = {{0,0,0,0},{0,0,0,0},{0,0,0,0}};
            #pragma unroll
            for (int ks = 0; ks < 5; ks++) {
                short8 bh = *(const short8*)&khB[kbase + ks * 32];
                short8 bl = *(const short8*)&klB[kbase + ks * 32];
                a0[0] = __builtin_amdgcn_mfma_f32_16x16x32_bf16(aqh[0][ks], bh, a0[0], 0, 0, 0);
                a0[1] = __builtin_amdgcn_mfma_f32_16x16x32_bf16(aql[0][ks], bh, a0[1], 0, 0, 0);
                a0[2] = __builtin_amdgcn_mfma_f32_16x16x32_bf16(aqh[0][ks], bl, a0[2], 0, 0, 0);
                a1[0] = __builtin_amdgcn_mfma_f32_16x16x32_bf16(aqh[1][ks], bh, a1[0], 0, 0, 0);
                a1[1] = __builtin_amdgcn_mfma_f32_16x16x32_bf16(aql[1][ks], bh, a1[1], 0, 0, 0);
                a1[2] = __builtin_amdgcn_mfma_f32_16x16x32_bf16(aqh[1][ks], bl, a1[2], 0, 0, 0);
            }
            #pragma unroll
            for (int r = 0; r < 4; r++) {
                float e0 = a0[0][r] + a0[1][r] + a0[2][r];
                float e1 = a1[0][r] + a1[1][r] + a1[2][r];
                unsigned short pb0 = f2bf(__expf(e0 - SHIFT));
                unsigned short pb1 = f2bf(__expf(e1 - SHIFT));
                Pb[(size_t)(i0 + l4 * 4 + r) * NN + tok] = pb0;
                Pb[(size_t)(i0 + 16 + l4 * 4 + r) * NN + tok] = pb1;
                sr[0][r] += bf2f(pb0);
                sr[1][r] += bf2f(pb1);
            }
        }
    }

    #pragma unroll
    for (int rt = 0; rt < 2; rt++)
        #pragma unroll
        for (int r = 0; r < 4; r++) {
            float v = sr[rt][r];
            v += __shfl_xor(v, 1);
            v += __shfl_xor(v, 2);
            v += __shfl_xor(v, 4);
            v += __shfl_xor(v, 8);
            if (l15 == 0) sums[wave][rt * 16 + l4 * 4 + r] = v;
        }
    __syncthreads();
    if (tid < 32)
        Lsum[(size_t)b * NN + i0 + tid] =
            sums[0][tid] + sums[1][tid] + sums[2][tid] + sums[3][tid];
}

// ---------------- Kernel 2b v4: counted-vmcnt depth-3 pipeline ----------------
// 128x128 tile, BK=32, 256 threads, 3-slot rotating LDS (48 KB -> 3 blk/CU).
// Per K-step: s_waitcnt vmcnt(8) [own tile-t loads done] -> s_barrier
// [cross-wave visibility] -> COMPUTE -> s_barrier [slot free] -> STAGE(t+3).
// NO vmcnt(0) drain in the loop (T4); each tile's loads have ~2 K-steps to
// land. Granule-transposed linear LDS layout (0 bank conflicts, refcheck'd
// in rounds 1-2): p(row,c16) = (row>>3)*32 + c16*8 + (row&7); global SOURCE
// carries the permutation, LDS dest linear (rule #21).
// XCD swizzle: b = bid&7 (one batch per XCD), n-fastest tile order.
__device__ __forceinline__ void gl16(const unsigned short* g, unsigned short* l) {
    __builtin_amdgcn_global_load_lds(
        (const __attribute__((address_space(1))) unsigned int*)g,
        (__attribute__((address_space(3))) unsigned int*)l, 16, 0, 0);
}

#define PV_SLOT (1024 * 8)   // shorts per slot: 512 A-granules + 512 B-granules

__global__ __launch_bounds__(256, 3) void pv_gemm(
    const unsigned short* __restrict__ P, const unsigned short* __restrict__ vt,
    const float* __restrict__ Lsum,
    const float* __restrict__ x, float* __restrict__ out)
{
    __shared__ __align__(16) unsigned short Sm[3 * PV_SLOT];   // 48 KiB

    const int p0 = blockIdx.x;          // 0..1279
    const int b  = p0 & 7;              // one batch per XCD
    const int t  = p0 >> 3;             // 0..159
    const int n0 = (t % 10) * 128;
    const int m0 = (t / 10) * 128;

    const int tid = threadIdx.x;
    const int wave = tid >> 6, lane = tid & 63;
    const int l15 = lane & 15, l4 = lane >> 4;
    const int qa = l15 >> 3, rl = l15 & 7;

    const unsigned short* Pb  = P  + (size_t)b * NN * NN;
    const unsigned short* vtb = vt + (size_t)b * LL * NN;

    floatx4 acc[2][8] = {};

    // precomputed per-thread staging coordinates (2 granules x (A,B))
    const int sp0 = tid,       sp1 = 256 + tid;
    const int srow0 = ((sp0 >> 5) << 3) + (sp0 & 7);
    const int srow1 = ((sp1 >> 5) << 3) + (sp1 & 7);
    const int sc8_0 = ((sp0 >> 3) & 3) * 8;
    const int sc8_1 = ((sp1 >> 3) & 3) * 8;

    auto STAGE = [&](int slot, int kt) {
        unsigned short* A  = Sm + slot * PV_SLOT;
        unsigned short* Bs = A + 512 * 8;
        const int k0 = kt * 32;
        gl16(Pb  + (size_t)(m0 + srow0) * NN + k0 + sc8_0, A  + sp0 * 8);
        gl16(vtb + (size_t)(n0 + srow0) * NN + k0 + sc8_0, Bs + sp0 * 8);
        gl16(Pb  + (size_t)(m0 + srow1) * NN + k0 + sc8_1, A  + sp1 * 8);
        gl16(vtb + (size_t)(n0 + srow1) * NN + k0 + sc8_1, Bs + sp1 * 8);
    };

    auto COMPUTE = [&](int slot) {
        const unsigned short* A  = Sm + slot * PV_SLOT;
        const unsigned short* Bs = A + 512 * 8;
        const int pa0 = (wave * 4 + qa) * 32 + l4 * 8 + rl;   // rows wave*32+l15
        short8 af0 = *(const short8*)(A + pa0 * 8);
        short8 af1 = *(const short8*)(A + (pa0 + 64) * 8);    // rows +16
        #pragma unroll
        for (int ct = 0; ct < 8; ct++) {
            int pb = (ct * 2 + qa) * 32 + l4 * 8 + rl;        // rows ct*16+l15
            short8 bf = *(const short8*)(Bs + pb * 8);
            acc[0][ct] = __builtin_amdgcn_mfma_f32_16x16x32_bf16(af0, bf, acc[0][ct], 0, 0, 0);
            acc[1][ct] = __builtin_amdgcn_mfma_f32_16x16x32_bf16(af1, bf, acc[1][ct], 0, 0, 0);
        }
    };

    // prologue: 3 tiles in flight (12 loads/thread)
    STAGE(0, 0); STAGE(1, 1); STAGE(2, 2);

    int s = 0;
    for (int kt = 0; kt < 61; ++kt) {
        asm volatile("s_waitcnt vmcnt(8)" ::: "memory");   // tile kt landed (own)
        asm volatile("s_barrier" ::: "memory");            // all waves' loads visible
        COMPUTE(s);
        asm volatile("s_barrier" ::: "memory");            // slot free for reuse
        STAGE(s, kt + 3);
        s = (s == 2) ? 0 : s + 1;
    }
    // epilogue: tiles 61,62,63 — drain 8 -> 4 -> 0
    asm volatile("s_waitcnt vmcnt(8)" ::: "memory");
    asm volatile("s_barrier" ::: "memory");
    COMPUTE(s); s = (s == 2) ? 0 : s + 1;
    asm volatile("s_waitcnt vmcnt(4)" ::: "memory");
    asm volatile("s_barrier" ::: "memory");
    COMPUTE(s); s = (s == 2) ? 0 : s + 1;
    asm volatile("s_waitcnt vmcnt(0)" ::: "memory");
    asm volatile("s_barrier" ::: "memory");
    COMPUTE(s);

    float linv[2][4];
    #pragma unroll
    for (int rt = 0; rt < 2; rt++)
        #pragma unroll
        for (int r = 0; r < 4; r++)
            linv[rt][r] = 1.0f / Lsum[(size_t)b * NN + m0 + wave * 32 + rt * 16 + l4 * 4 + r];

    #pragma unroll
    for (int rt = 0; rt < 2; rt++)
        #pragma unroll
        for (int ct = 0; ct < 8; ct++)
            #pragma unroll
            for (int r = 0; r < 4; r++) {
                int row = m0 + wave * 32 + rt * 16 + l4 * 4 + r;
                int col = n0 + ct * 16 + l15;
                size_t idx = ((size_t)b * NN + row) * LL + col;
                out[idx] = acc[rt][ct][r] * linv[rt][r] + x[idx];
            }
}

extern "C" void kernel_launch(void* const* d_in, const int* in_sizes, int n_in,
                              void* d_out, int out_size, void* d_ws, size_t ws_size,
                              hipStream_t stream) {
    const float* x  = (const float*)d_in[0];
    const float* Wq = (const float*)d_in[1];
    const float* bq = (const float*)d_in[2];
    const float* Wk = (const float*)d_in[3];
    const float* bk = (const float*)d_in[4];
    const float* Wv = (const float*)d_in[5];
    const float* bv = (const float*)d_in[6];
    float* out = (float*)d_out;

    // ws layout (~135 MB)
    unsigned short* wqk_h = (unsigned short*)d_ws;            // [320][LL]
    unsigned short* wqk_l = wqk_h + (size_t)2*HH * LL;        // [320][LL]
    unsigned short* wv    = wqk_l + (size_t)2*HH * LL;        // [LL][LL]
    unsigned short* qh    = wv    + (size_t)LL * LL;          // [BN][HH]
    unsigned short* ql    = qh    + (size_t)BN * HH;
    unsigned short* kh    = ql    + (size_t)BN * HH;
    unsigned short* kl    = kh    + (size_t)BN * HH;
    unsigned short* vt    = kl    + (size_t)BN * HH;          // [BB][LL][NN]
    unsigned short* P     = vt    + (size_t)BB * LL * NN;     // [BB][NN][NN]
    float*          Lsum  = (float*)(P + (size_t)BB * NN * NN); // [BN]

    cast_w<<<dim3(NO), dim3(256), 0, stream>>>(Wq, Wk, Wv, wqk_h, wqk_l, wv);

    dim3 gqk(2*HH / 64, BN / 128);         // (5, 128)
    proj_qk<<<gqk, dim3(256), 0, stream>>>(x, wqk_h, wqk_l, bq, bk, qh, ql, kh, kl);

    dim3 gv(LL / 128, BN / 128);           // (10, 128)
    proj_v<<<gv, dim3(256), 0, stream>>>(x, wv, bv, vt);

    dim3 gs(NN / 32, BB);                  // (64, 8)
    s_exp<<<gs, dim3(256), 0, stream>>>(qh, ql, kh, kl, P, Lsum);

    // flat 1280 blocks: b = bid&7 (batch per XCD), t = bid>>3 -> (n,m) tile
    pv_gemm<<<dim3(1280), dim3(256), 0, stream>>>(P, vt, Lsum, x, out);
}